// Round 5
// baseline (297.416 us; speedup 1.0000x reference)
//
#include <hip/hip_runtime.h>
#include <hip/hip_bf16.h>
#include <cstdint>

typedef unsigned short u16;
typedef unsigned int   u32;

typedef __attribute__((ext_vector_type(8))) short short8;   // 8 x bf16 (4 VGPRs)
typedef __attribute__((ext_vector_type(4))) float f32x4;    // MFMA accumulator

__device__ __forceinline__ float b2f(u16 v) { return __uint_as_float(((u32)v) << 16); }
__device__ __forceinline__ u16 f2b(float f) {
    u32 u = __float_as_uint(f);
    u += 0x7FFFu + ((u >> 16) & 1u);   // round-to-nearest-even
    return (u16)(u >> 16);
}

#define G2L16(gp, lp) __builtin_amdgcn_global_load_lds(                       \
    (const __attribute__((address_space(1))) void*)(gp),                      \
    (__attribute__((address_space(3))) void*)(lp), 16, 0, 0)

// ---------------------------------------------------------------------------
// Fused prologue (all independent work, one dispatch):
//   blocks [0,1024)      : W1 (1024x1024 f32) -> W1t (bf16, transposed)
//   blocks [1024,2048)   : W2 -> W2t
//   blocks [2048,6144)   : Wg (2048x2048) -> Wgt
//   blocks [6144,14336)  : cast iQ f32 -> iQb bf16
//   blocks [14336,14592) : chunk sums of iV (64 chunks of 32 rows per batch)
// ---------------------------------------------------------------------------
__device__ __forceinline__ void transpose_body(const float* __restrict__ in,
                                               u16* __restrict__ out,
                                               int R, int C, int lb, int tilesX,
                                               float (*tile)[33]) {
    const int bx = (lb % tilesX) * 32;
    const int by = (lb / tilesX) * 32;
    const int tx = threadIdx.x & 31, ty = threadIdx.x >> 5;   // 32 x 8
    #pragma unroll
    for (int i = 0; i < 32; i += 8)
        tile[ty + i][tx] = in[(size_t)(by + ty + i) * C + (bx + tx)];
    __syncthreads();
    #pragma unroll
    for (int i = 0; i < 32; i += 8)
        out[(size_t)(bx + ty + i) * R + (by + tx)] = f2b(tile[tx][ty + i]);
}

__global__ void prologue_kernel(const float* __restrict__ W1, u16* __restrict__ W1t,
                                const float* __restrict__ W2, u16* __restrict__ W2t,
                                const float* __restrict__ Wg, u16* __restrict__ Wgt,
                                const float* __restrict__ iQ, u16* __restrict__ iQb,
                                const float* __restrict__ iV, float* __restrict__ csum) {
    __shared__ float tile[32][33];
    const int bid = blockIdx.x;
    const int tid = threadIdx.x;
    if (bid < 1024) {
        transpose_body(W1, W1t, 1024, 1024, bid, 32, tile);
    } else if (bid < 2048) {
        transpose_body(W2, W2t, 1024, 1024, bid - 1024, 32, tile);
    } else if (bid < 6144) {
        transpose_body(Wg, Wgt, 2048, 2048, bid - 2048, 64, tile);
    } else if (bid < 14336) {
        const size_t i = ((size_t)(bid - 6144) * 256 + tid) * 4;
        const float4 v = *(const float4*)(iQ + i);
        ushort4 o;
        o.x = f2b(v.x); o.y = f2b(v.y); o.z = f2b(v.z); o.w = f2b(v.w);
        *(ushort4*)(iQb + i) = o;
    } else {
        // chunk sums: 32-row chunks, 64 chunks per batch, 4 batches -> 256 blocks
        const int idx = bid - 14336;
        const int b = idx >> 6, c = idx & 63;
        const int d = tid * 4;                              // D = 1024
        const float* src = iV + ((size_t)(b * 2048 + c * 32)) * 1024 + d;
        float4 s = {0.f, 0.f, 0.f, 0.f};
        #pragma unroll 8
        for (int i = 0; i < 32; ++i) {
            const float4 v = *(const float4*)(src + (size_t)i * 1024);
            s.x += v.x; s.y += v.y; s.z += v.z; s.w += v.w;
        }
        *(float4*)(csum + ((size_t)(b * 64 + c)) * 1024 + d) = s;
    }
}

// ---------------------------------------------------------------------------
// In-place inclusive prefix over the 64 chunk sums. 4096 independent scans
// (one per (batch,d)), 16 blocks x 256 threads.
// ---------------------------------------------------------------------------
__global__ void csum_prefix_kernel(float* __restrict__ csum) {
    const int g = blockIdx.x * 256 + threadIdx.x;   // 0..4095
    const int b = g >> 10, d = g & 1023;
    float* p = csum + (size_t)b * 64 * 1024 + d;
    float run = 0.f;
    #pragma unroll 8
    for (int c = 0; c < 64; ++c) {
        run += p[(size_t)c * 1024];
        p[(size_t)c * 1024] = run;
    }
}

// ---------------------------------------------------------------------------
// Scan: single prefix load + in-chunk streaming scan -> avg (bf16). 256 blocks.
// ---------------------------------------------------------------------------
__global__ void scan_kernel(const float* __restrict__ iV, const float* __restrict__ csum,
                            u16* __restrict__ avg) {
    const int c = blockIdx.x & 63, b = blockIdx.x >> 6;
    const int d = threadIdx.x * 4;
    float4 acc = {0.f, 0.f, 0.f, 0.f};
    if (c > 0) acc = *(const float4*)(csum + ((size_t)(b * 64 + c - 1)) * 1024 + d);

    const size_t off = ((size_t)(b * 2048 + c * 32)) * 1024 + d;
    const float* src = iV + off;
    u16*         dst = avg + off;
    const int s0 = c * 32;
    #pragma unroll 4
    for (int i = 0; i < 32; ++i) {
        const float4 v = *(const float4*)(src + (size_t)i * 1024);
        acc.x += v.x; acc.y += v.y; acc.z += v.z; acc.w += v.w;
        const float inv = 1.0f / (float)(s0 + i + 1);
        ushort4 o;
        o.x = f2b(acc.x * inv); o.y = f2b(acc.y * inv);
        o.z = f2b(acc.z * inv); o.w = f2b(acc.w * inv);
        *(ushort4*)(dst + (size_t)i * 1024) = o;
    }
}

// ---------------------------------------------------------------------------
// MFMA GEMM, BK=64, XOR-swizzled LDS (conflict-free ds_read_b128).
// 128x128 block, 4 waves (2x2 of 64x64), acc = 64 VGPRs/wave -> 3 waves/SIMD.
// EPI: 0 = relu(x+b), 1 = x+b.
// ---------------------------------------------------------------------------
template <int EPI>
__global__ __launch_bounds__(256, 3)
void gemm_kernel(const u16* __restrict__ A, const u16* __restrict__ Bt,
                 const float* __restrict__ bias, u16* __restrict__ C,
                 int M, int N, int K) {
    __shared__ u16 As[128 * 64];
    __shared__ u16 Bs[128 * 64];

    const int tid  = threadIdx.x;
    const int m0   = blockIdx.x * 128;
    const int n0   = blockIdx.y * 128;
    const int wave = tid >> 6, lane = tid & 63;
    const int wm   = (wave & 1) << 6;
    const int wn   = (wave >> 1) << 6;
    const int quad = lane >> 4, l16 = lane & 15;

    f32x4 acc[4][4];
    #pragma unroll
    for (int i = 0; i < 4; ++i)
        #pragma unroll
        for (int j = 0; j < 4; ++j) acc[i][j] = (f32x4){0.f, 0.f, 0.f, 0.f};

    int oo[4], rr[4], qq[4];
    #pragma unroll
    for (int j = 0; j < 4; ++j) {
        oo[j] = tid * 16 + j * 4096;
        rr[j] = oo[j] >> 7;
        qq[j] = ((oo[j] >> 4) & 7) ^ (rr[j] & 7);
    }

    const int ktiles = K >> 6;
    for (int kt = 0; kt < ktiles; ++kt) {
        const int kb = kt << 6;
        #pragma unroll
        for (int j = 0; j < 4; ++j) {
            G2L16((const char*)A  + ((size_t)(m0 + rr[j]) * K + kb) * 2 + qq[j] * 16,
                  (char*)As + oo[j]);
            G2L16((const char*)Bt + ((size_t)(n0 + rr[j]) * K + kb) * 2 + qq[j] * 16,
                  (char*)Bs + oo[j]);
        }
        __syncthreads();

        #pragma unroll
        for (int h = 0; h < 2; ++h) {
            short8 af[4], bf[4];
            #pragma unroll
            for (int mi = 0; mi < 4; ++mi) {
                const int R = wm + mi * 16 + l16;
                af[mi] = *(const short8*)(As + R * 64 + ((((h << 2) | quad) ^ (R & 7)) << 3));
            }
            #pragma unroll
            for (int ni = 0; ni < 4; ++ni) {
                const int R = wn + ni * 16 + l16;
                bf[ni] = *(const short8*)(Bs + R * 64 + ((((h << 2) | quad) ^ (R & 7)) << 3));
            }
            #pragma unroll
            for (int mi = 0; mi < 4; ++mi)
                #pragma unroll
                for (int ni = 0; ni < 4; ++ni)
                    acc[mi][ni] = __builtin_amdgcn_mfma_f32_16x16x32_bf16(
                        af[mi], bf[ni], acc[mi][ni], 0, 0, 0);
        }
        __syncthreads();
    }

    #pragma unroll
    for (int ni = 0; ni < 4; ++ni) {
        const int col = n0 + wn + ni * 16 + l16;
        const float bv = bias[col];
        #pragma unroll
        for (int mi = 0; mi < 4; ++mi) {
            const int row0 = m0 + wm + mi * 16 + quad * 4;
            #pragma unroll
            for (int r = 0; r < 4; ++r) {
                float v = acc[mi][ni][r] + bv;
                if (EPI == 0) v = fmaxf(v, 0.f);
                C[(size_t)(row0 + r) * N + col] = f2b(v);
            }
        }
    }
}

// ---------------------------------------------------------------------------
// Fused GEMM3 + sigmoid + gate, low-register variant.
// Block tile: 128 rows x 64 out-cols, BOTH gate pages. 4 waves:
//   wave = (page<<1)|mhalf ; each wave computes 64x64 (acc = 64 regs).
// Page 1 (fgate) passes its sigmoid through LDS (reusing staging buffer);
// page 0 waves write out = gi*iQ + gf*ffn (f32).
// ---------------------------------------------------------------------------
__global__ __launch_bounds__(256, 3)
void gemm_gate_kernel(const u16* __restrict__ iQb, const u16* __restrict__ ffn,
                      const u16* __restrict__ Wgt, const float* __restrict__ bg,
                      const float* __restrict__ iQ, float* __restrict__ out,
                      int M, int D2 /*2048*/) {
    __shared__ __align__(16) char smem[32768];
    u16*   As    = (u16*)smem;               // 128 x 64 bf16 = 16KB
    u16*   Bs0   = (u16*)(smem + 16384);     //  64 x 64 bf16 =  8KB (igate cols)
    u16*   Bs1   = (u16*)(smem + 24576);     //  64 x 64 bf16 =  8KB (fgate cols)
    float* gfbuf = (float*)smem;             // 128 x 64 f32 = 32KB (epilogue overlay)

    const int tid  = threadIdx.x;
    const int m0   = blockIdx.x * 128;
    const int n0   = blockIdx.y * 64;           // out-col tile, n0 < 1024
    const int wave = tid >> 6, lane = tid & 63;
    const int page = wave >> 1;                 // 0 = igate, 1 = fgate
    const int mh   = (wave & 1) << 6;           // m-half
    const int quad = lane >> 4, l16 = lane & 15;
    const int D = D2 >> 1;                      // 1024

    f32x4 acc[4][4];
    #pragma unroll
    for (int i = 0; i < 4; ++i)
        #pragma unroll
        for (int j = 0; j < 4; ++j) acc[i][j] = (f32x4){0.f, 0.f, 0.f, 0.f};

    // staging offsets: As 4 issues (rows 0..127), Bs0/Bs1 2 issues each (rows 0..63)
    int oa[4], ra[4], qa[4];
    #pragma unroll
    for (int j = 0; j < 4; ++j) {
        oa[j] = tid * 16 + j * 4096;
        ra[j] = oa[j] >> 7;
        qa[j] = ((oa[j] >> 4) & 7) ^ (ra[j] & 7);
    }
    int ob[2], rb[2], qb[2];
    #pragma unroll
    for (int j = 0; j < 2; ++j) {
        ob[j] = tid * 16 + j * 4096;
        rb[j] = ob[j] >> 7;
        qb[j] = ((ob[j] >> 4) & 7) ^ (rb[j] & 7);
    }

    const int ktiles = D2 >> 6;                 // 32
    for (int kt = 0; kt < ktiles; ++kt) {
        const int kb = kt << 6;
        const char* Ab = (const char*)((kb < D) ? (iQb + kb) : (ffn + (kb - D)));
        const char* B0 = (const char*)(Wgt + (size_t)n0 * D2 + kb);
        const char* B1 = (const char*)(Wgt + (size_t)(n0 + D) * D2 + kb);
        #pragma unroll
        for (int j = 0; j < 4; ++j)
            G2L16(Ab + (size_t)(m0 + ra[j]) * D * 2 + qa[j] * 16, (char*)As + oa[j]);
        #pragma unroll
        for (int j = 0; j < 2; ++j) {
            G2L16(B0 + (size_t)rb[j] * D2 * 2 + qb[j] * 16, (char*)Bs0 + ob[j]);
            G2L16(B1 + (size_t)rb[j] * D2 * 2 + qb[j] * 16, (char*)Bs1 + ob[j]);
        }
        __syncthreads();

        const u16* Bsp = page ? Bs1 : Bs0;
        #pragma unroll
        for (int h = 0; h < 2; ++h) {
            short8 af[4], bf[4];
            #pragma unroll
            for (int mi = 0; mi < 4; ++mi) {
                const int R = mh + mi * 16 + l16;
                af[mi] = *(const short8*)(As + R * 64 + ((((h << 2) | quad) ^ (R & 7)) << 3));
            }
            #pragma unroll
            for (int ni = 0; ni < 4; ++ni) {
                const int R = ni * 16 + l16;
                bf[ni] = *(const short8*)(Bsp + R * 64 + ((((h << 2) | quad) ^ (R & 7)) << 3));
            }
            #pragma unroll
            for (int mi = 0; mi < 4; ++mi)
                #pragma unroll
                for (int ni = 0; ni < 4; ++ni)
                    acc[mi][ni] = __builtin_amdgcn_mfma_f32_16x16x32_bf16(
                        af[mi], bf[ni], acc[mi][ni], 0, 0, 0);
        }
        __syncthreads();   // also protects gfbuf overlay after the last iter
    }

    // sigmoid in place
    #pragma unroll
    for (int ni = 0; ni < 4; ++ni) {
        const int colg = n0 + ni * 16 + l16;
        const float bv = bg[page ? colg + D : colg];
        #pragma unroll
        for (int mi = 0; mi < 4; ++mi)
            #pragma unroll
            for (int r = 0; r < 4; ++r)
                acc[mi][ni][r] = 1.0f / (1.0f + __expf(-(acc[mi][ni][r] + bv)));
    }

    if (page == 1) {
        #pragma unroll
        for (int ni = 0; ni < 4; ++ni)
            #pragma unroll
            for (int mi = 0; mi < 4; ++mi)
                #pragma unroll
                for (int r = 0; r < 4; ++r)
                    gfbuf[(mh + mi * 16 + quad * 4 + r) * 64 + ni * 16 + l16] =
                        acc[mi][ni][r];
    }
    __syncthreads();
    if (page == 0) {
        #pragma unroll
        for (int ni = 0; ni < 4; ++ni) {
            const int col = ni * 16 + l16;
            #pragma unroll
            for (int mi = 0; mi < 4; ++mi) {
                #pragma unroll
                for (int r = 0; r < 4; ++r) {
                    const int row = mh + mi * 16 + quad * 4 + r;
                    const size_t idx = (size_t)(m0 + row) * D + n0 + col;
                    out[idx] = acc[mi][ni][r] * iQ[idx] +
                               gfbuf[row * 64 + col] * b2f(ffn[idx]);
                }
            }
        }
    }
}

// ---------------------------------------------------------------------------
extern "C" void kernel_launch(void* const* d_in, const int* in_sizes, int n_in,
                              void* d_out, int out_size, void* d_ws, size_t ws_size,
                              hipStream_t stream) {
    const int B = 4, S = 2048, D = 1024, D2 = 2048;
    const int M = B * S;  // 8192

    const float* iQ = (const float*)d_in[0];
    const float* iV = (const float*)d_in[1];
    const float* W1 = (const float*)d_in[2];
    const float* b1 = (const float*)d_in[3];
    const float* W2 = (const float*)d_in[4];
    const float* b2 = (const float*)d_in[5];
    const float* Wg = (const float*)d_in[6];
    const float* bg = (const float*)d_in[7];
    float* out = (float*)d_out;

    // workspace, no aliasing (61 MB):
    u16*   regA = (u16*)d_ws;                    // avg -> ffn   (16 MB)
    u16*   regB = regA + (size_t)M * D;          // h            (16 MB)
    u16*   iQb  = regB + (size_t)M * D;          // iQ bf16      (16 MB)
    u16*   W1t  = iQb  + (size_t)M * D;          //              ( 2 MB)
    u16*   W2t  = W1t  + (size_t)D * D;          //              ( 2 MB)
    u16*   Wgt  = W2t  + (size_t)D * D;          //              ( 8 MB)
    float* csum = (float*)(Wgt + (size_t)D2 * D2); // B*64*D f32 ( 1 MB)

    u16* avg = regA;
    u16* ffn = regA;
    u16* h   = regB;

    // 1. all independent prologue work in one big dispatch (14592 blocks)
    prologue_kernel<<<14592, 256, 0, stream>>>(W1, W1t, W2, W2t, Wg, Wgt,
                                               iQ, iQb, iV, csum);
    // 2a. hierarchical prefix over chunk sums
    csum_prefix_kernel<<<16, 256, 0, stream>>>(csum);
    // 2b. causal cumulative mean (streaming)
    scan_kernel<<<B * 64, 256, 0, stream>>>(iV, csum, avg);
    // 3. h = relu(avg @ W1 + b1)
    gemm_kernel<0><<<dim3(M / 128, D / 128), 256, 0, stream>>>(avg, W1t, b1, h, M, D, D);
    // 4. ffn = h @ W2 + b2   (overlays avg)
    gemm_kernel<1><<<dim3(M / 128, D / 128), 256, 0, stream>>>(h, W2t, b2, ffn, M, D, D);
    // 5. fused gate GEMM + epilogue (block = 128 x 64-dual)
    gemm_gate_kernel<<<dim3(M / 128, D / 64), 256, 0, stream>>>(
        iQb, ffn, Wgt, bg, iQ, out, M, D2);
}

// Round 6
// 277.003 us; speedup vs baseline: 1.0737x; 1.0737x over previous
//
#include <hip/hip_runtime.h>
#include <hip/hip_bf16.h>
#include <cstdint>

typedef unsigned short u16;
typedef unsigned int   u32;

typedef __attribute__((ext_vector_type(8))) short short8;   // 8 x bf16 (4 VGPRs)
typedef __attribute__((ext_vector_type(4))) float f32x4;    // MFMA accumulator

__device__ __forceinline__ float b2f(u16 v) { return __uint_as_float(((u32)v) << 16); }
__device__ __forceinline__ u16 f2b(float f) {
    u32 u = __float_as_uint(f);
    u += 0x7FFFu + ((u >> 16) & 1u);   // round-to-nearest-even
    return (u16)(u >> 16);
}

#define G2L16(gp, lp) __builtin_amdgcn_global_load_lds(                       \
    (const __attribute__((address_space(1))) void*)(gp),                      \
    (__attribute__((address_space(3))) void*)(lp), 16, 0, 0)

// ---------------------------------------------------------------------------
// Fused prologue (all independent work, one dispatch):
//   blocks [0,1024)      : W1 (1024x1024 f32) -> W1t (bf16, transposed)
//   blocks [1024,2048)   : W2 -> W2t
//   blocks [2048,6144)   : Wg (2048x2048) -> Wgt
//   blocks [6144,14336)  : cast iQ f32 -> iQb bf16
//   blocks [14336,14592) : chunk sums of iV (64 chunks of 32 rows per batch)
// ---------------------------------------------------------------------------
__device__ __forceinline__ void transpose_body(const float* __restrict__ in,
                                               u16* __restrict__ out,
                                               int R, int C, int lb, int tilesX,
                                               float (*tile)[33]) {
    const int bx = (lb % tilesX) * 32;
    const int by = (lb / tilesX) * 32;
    const int tx = threadIdx.x & 31, ty = threadIdx.x >> 5;   // 32 x 8
    #pragma unroll
    for (int i = 0; i < 32; i += 8)
        tile[ty + i][tx] = in[(size_t)(by + ty + i) * C + (bx + tx)];
    __syncthreads();
    #pragma unroll
    for (int i = 0; i < 32; i += 8)
        out[(size_t)(bx + ty + i) * R + (by + tx)] = f2b(tile[tx][ty + i]);
}

__global__ void prologue_kernel(const float* __restrict__ W1, u16* __restrict__ W1t,
                                const float* __restrict__ W2, u16* __restrict__ W2t,
                                const float* __restrict__ Wg, u16* __restrict__ Wgt,
                                const float* __restrict__ iQ, u16* __restrict__ iQb,
                                const float* __restrict__ iV, float* __restrict__ csum) {
    __shared__ float tile[32][33];
    const int bid = blockIdx.x;
    const int tid = threadIdx.x;
    if (bid < 1024) {
        transpose_body(W1, W1t, 1024, 1024, bid, 32, tile);
    } else if (bid < 2048) {
        transpose_body(W2, W2t, 1024, 1024, bid - 1024, 32, tile);
    } else if (bid < 6144) {
        transpose_body(Wg, Wgt, 2048, 2048, bid - 2048, 64, tile);
    } else if (bid < 14336) {
        const size_t i = ((size_t)(bid - 6144) * 256 + tid) * 4;
        const float4 v = *(const float4*)(iQ + i);
        ushort4 o;
        o.x = f2b(v.x); o.y = f2b(v.y); o.z = f2b(v.z); o.w = f2b(v.w);
        *(ushort4*)(iQb + i) = o;
    } else {
        // chunk sums: 32-row chunks, 64 chunks per batch, 4 batches -> 256 blocks
        const int idx = bid - 14336;
        const int b = idx >> 6, c = idx & 63;
        const int d = tid * 4;                              // D = 1024
        const float* src = iV + ((size_t)(b * 2048 + c * 32)) * 1024 + d;
        float4 s = {0.f, 0.f, 0.f, 0.f};
        #pragma unroll 8
        for (int i = 0; i < 32; ++i) {
            const float4 v = *(const float4*)(src + (size_t)i * 1024);
            s.x += v.x; s.y += v.y; s.z += v.z; s.w += v.w;
        }
        *(float4*)(csum + ((size_t)(b * 64 + c)) * 1024 + d) = s;
    }
}

// ---------------------------------------------------------------------------
// Scan: prefix over chunk sums (4-way ILP) + in-chunk serial scan -> avg (bf16).
// ---------------------------------------------------------------------------
__global__ void scan_kernel(const float* __restrict__ iV, const float* __restrict__ csum,
                            u16* __restrict__ avg) {
    const int c = blockIdx.x & 63, b = blockIdx.x >> 6;
    const int d = threadIdx.x * 4;
    const float* cs = csum + (size_t)b * 64 * 1024 + d;
    float4 a0 = {0,0,0,0}, a1 = {0,0,0,0}, a2 = {0,0,0,0}, a3 = {0,0,0,0};
    int cc = 0;
    for (; cc + 4 <= c; cc += 4) {
        const float4 v0 = *(const float4*)(cs + (size_t)(cc + 0) * 1024);
        const float4 v1 = *(const float4*)(cs + (size_t)(cc + 1) * 1024);
        const float4 v2 = *(const float4*)(cs + (size_t)(cc + 2) * 1024);
        const float4 v3 = *(const float4*)(cs + (size_t)(cc + 3) * 1024);
        a0.x += v0.x; a0.y += v0.y; a0.z += v0.z; a0.w += v0.w;
        a1.x += v1.x; a1.y += v1.y; a1.z += v1.z; a1.w += v1.w;
        a2.x += v2.x; a2.y += v2.y; a2.z += v2.z; a2.w += v2.w;
        a3.x += v3.x; a3.y += v3.y; a3.z += v3.z; a3.w += v3.w;
    }
    for (; cc < c; ++cc) {
        const float4 v = *(const float4*)(cs + (size_t)cc * 1024);
        a0.x += v.x; a0.y += v.y; a0.z += v.z; a0.w += v.w;
    }
    float4 acc;
    acc.x = (a0.x + a1.x) + (a2.x + a3.x);
    acc.y = (a0.y + a1.y) + (a2.y + a3.y);
    acc.z = (a0.z + a1.z) + (a2.z + a3.z);
    acc.w = (a0.w + a1.w) + (a2.w + a3.w);

    const size_t off = ((size_t)(b * 2048 + c * 32)) * 1024 + d;
    const float* src = iV + off;
    u16*         dst = avg + off;
    const int s0 = c * 32;
    #pragma unroll 4
    for (int i = 0; i < 32; ++i) {
        const float4 v = *(const float4*)(src + (size_t)i * 1024);
        acc.x += v.x; acc.y += v.y; acc.z += v.z; acc.w += v.w;
        const float inv = 1.0f / (float)(s0 + i + 1);
        ushort4 o;
        o.x = f2b(acc.x * inv); o.y = f2b(acc.y * inv);
        o.z = f2b(acc.z * inv); o.w = f2b(acc.w * inv);
        *(ushort4*)(dst + (size_t)i * 1024) = o;
    }
}

// ---------------------------------------------------------------------------
// MFMA GEMM, BK=64, 8-slot XOR-swizzled LDS (round-4 config — measured good).
// 128x128 block, 4 waves, 4x4 16x16x32 frags/wave.  EPI: 0 = relu, 1 = none.
// ---------------------------------------------------------------------------
template <int EPI>
__global__ __launch_bounds__(256, 2)
void gemm_kernel(const u16* __restrict__ A, const u16* __restrict__ Bt,
                 const float* __restrict__ bias, u16* __restrict__ C,
                 int M, int N, int K) {
    __shared__ u16 As[128 * 64];
    __shared__ u16 Bs[128 * 64];

    const int tid  = threadIdx.x;
    const int m0   = blockIdx.x * 128;
    const int n0   = blockIdx.y * 128;
    const int wave = tid >> 6, lane = tid & 63;
    const int wm   = (wave & 1) << 6;
    const int wn   = (wave >> 1) << 6;
    const int quad = lane >> 4, l16 = lane & 15;

    f32x4 acc[4][4];
    #pragma unroll
    for (int i = 0; i < 4; ++i)
        #pragma unroll
        for (int j = 0; j < 4; ++j) acc[i][j] = (f32x4){0.f, 0.f, 0.f, 0.f};

    int oo[4], rr[4], qq[4];
    #pragma unroll
    for (int j = 0; j < 4; ++j) {
        oo[j] = tid * 16 + j * 4096;
        rr[j] = oo[j] >> 7;
        qq[j] = ((oo[j] >> 4) & 7) ^ (rr[j] & 7);
    }

    const int ktiles = K >> 6;
    for (int kt = 0; kt < ktiles; ++kt) {
        const int kb = kt << 6;
        #pragma unroll
        for (int j = 0; j < 4; ++j) {
            G2L16((const char*)A  + ((size_t)(m0 + rr[j]) * K + kb) * 2 + qq[j] * 16,
                  (char*)As + oo[j]);
            G2L16((const char*)Bt + ((size_t)(n0 + rr[j]) * K + kb) * 2 + qq[j] * 16,
                  (char*)Bs + oo[j]);
        }
        __syncthreads();

        #pragma unroll
        for (int h = 0; h < 2; ++h) {
            short8 af[4], bf[4];
            #pragma unroll
            for (int mi = 0; mi < 4; ++mi) {
                const int R = wm + mi * 16 + l16;
                af[mi] = *(const short8*)(As + R * 64 + ((((h << 2) | quad) ^ (R & 7)) << 3));
            }
            #pragma unroll
            for (int ni = 0; ni < 4; ++ni) {
                const int R = wn + ni * 16 + l16;
                bf[ni] = *(const short8*)(Bs + R * 64 + ((((h << 2) | quad) ^ (R & 7)) << 3));
            }
            #pragma unroll
            for (int mi = 0; mi < 4; ++mi)
                #pragma unroll
                for (int ni = 0; ni < 4; ++ni)
                    acc[mi][ni] = __builtin_amdgcn_mfma_f32_16x16x32_bf16(
                        af[mi], bf[ni], acc[mi][ni], 0, 0, 0);
        }
        __syncthreads();
    }

    #pragma unroll
    for (int ni = 0; ni < 4; ++ni) {
        const int col = n0 + wn + ni * 16 + l16;
        const float bv = bias[col];
        #pragma unroll
        for (int mi = 0; mi < 4; ++mi) {
            const int row0 = m0 + wm + mi * 16 + quad * 4;
            #pragma unroll
            for (int r = 0; r < 4; ++r) {
                float v = acc[mi][ni][r] + bv;
                if (EPI == 0) v = fmaxf(v, 0.f);
                C[(size_t)(row0 + r) * N + col] = f2b(v);
            }
        }
    }
}

// ---------------------------------------------------------------------------
// Fused GEMM3 + sigmoid + gate.  Round-3 cadence (BK=32, dual page in-register)
// + 2-row-group XOR swizzle for conflict-free BK=32 LDS:
//   rows pair into 128B groups; chunk q (0..3) of row r lives at slot
//   ((r&1)*4+q) ^ ((r>>1)&7) within group r>>1.  Each slot is hit by exactly
//   2 lanes per wave access -> 2 lanes/bank (free).
// ---------------------------------------------------------------------------
__global__ __launch_bounds__(256, 2)
void gemm_gate_kernel(const u16* __restrict__ iQb, const u16* __restrict__ ffn,
                      const u16* __restrict__ Wgt, const float* __restrict__ bg,
                      const float* __restrict__ iQ, float* __restrict__ out,
                      int M, int D2 /*2048*/) {
    __shared__ u16 As [128 * 32];
    __shared__ u16 Bs0[128 * 32];
    __shared__ u16 Bs1[128 * 32];

    const int tid  = threadIdx.x;
    const int m0   = blockIdx.x * 128;
    const int n0   = blockIdx.y * 128;          // out-col tile, n0 < 1024
    const int wave = tid >> 6, lane = tid & 63;
    const int wm   = (wave & 1) << 6;
    const int wn   = (wave >> 1) << 6;
    const int quad = lane >> 4, l16 = lane & 15;
    const int D = D2 >> 1;                      // 1024

    f32x4 acc[2][4][4];
    #pragma unroll
    for (int p = 0; p < 2; ++p)
        #pragma unroll
        for (int i = 0; i < 4; ++i)
            #pragma unroll
            for (int j = 0; j < 4; ++j) acc[p][i][j] = (f32x4){0.f, 0.f, 0.f, 0.f};

    // staging: 2 issues of 4KB per buffer; 2-row-group swizzle
    int oo[2], grow[2], gcol[2];
    #pragma unroll
    for (int j = 0; j < 2; ++j) {
        oo[j] = tid * 16 + j * 4096;
        const int rp = oo[j] >> 7;              // row-group 0..63
        const int s  = (oo[j] >> 4) & 7;        // slot in group
        const int ch = s ^ (rp & 7);            // global chunk 0..7
        grow[j] = rp * 2 + (ch >> 2);           // global row 0..127
        gcol[j] = (ch & 3) * 16;                // byte offset in 64B k-window
    }

    const int ktiles = D2 >> 5;                 // 64
    for (int kt = 0; kt < ktiles; ++kt) {
        const int kb = kt << 5;
        const char* Ab = (const char*)((kb < D) ? (iQb + kb) : (ffn + (kb - D)));
        const char* B0 = (const char*)(Wgt + (size_t)n0 * D2 + kb);
        const char* B1 = (const char*)(Wgt + (size_t)(n0 + D) * D2 + kb);
        #pragma unroll
        for (int j = 0; j < 2; ++j) {
            G2L16(Ab + (size_t)(m0 + grow[j]) * D * 2 + gcol[j], (char*)As  + oo[j]);
            G2L16(B0 + (size_t)grow[j] * D2 * 2 + gcol[j],       (char*)Bs0 + oo[j]);
            G2L16(B1 + (size_t)grow[j] * D2 * 2 + gcol[j],       (char*)Bs1 + oo[j]);
        }
        __syncthreads();

        short8 af[4], bf0[4], bf1[4];
        #pragma unroll
        for (int mi = 0; mi < 4; ++mi) {
            const int R = wm + mi * 16 + l16;
            const int so = (R >> 1) * 64 +
                           (((((R & 1) << 2) | quad) ^ ((R >> 1) & 7)) << 3);
            af[mi] = *(const short8*)(As + so);
        }
        #pragma unroll
        for (int ni = 0; ni < 4; ++ni) {
            const int R = wn + ni * 16 + l16;
            const int so = (R >> 1) * 64 +
                           (((((R & 1) << 2) | quad) ^ ((R >> 1) & 7)) << 3);
            bf0[ni] = *(const short8*)(Bs0 + so);
            bf1[ni] = *(const short8*)(Bs1 + so);
        }
        #pragma unroll
        for (int mi = 0; mi < 4; ++mi)
            #pragma unroll
            for (int ni = 0; ni < 4; ++ni) {
                acc[0][mi][ni] = __builtin_amdgcn_mfma_f32_16x16x32_bf16(
                    af[mi], bf0[ni], acc[0][mi][ni], 0, 0, 0);
                acc[1][mi][ni] = __builtin_amdgcn_mfma_f32_16x16x32_bf16(
                    af[mi], bf1[ni], acc[1][mi][ni], 0, 0, 0);
            }
        __syncthreads();
    }

    #pragma unroll
    for (int ni = 0; ni < 4; ++ni) {
        const int col = n0 + wn + ni * 16 + l16;
        const float bgi = bg[col];
        const float bgf = bg[col + D];
        #pragma unroll
        for (int mi = 0; mi < 4; ++mi) {
            const int row0 = m0 + wm + mi * 16 + quad * 4;
            #pragma unroll
            for (int r = 0; r < 4; ++r) {
                const size_t idx = (size_t)(row0 + r) * D + col;
                const float gi = 1.0f / (1.0f + __expf(-(acc[0][mi][ni][r] + bgi)));
                const float gf = 1.0f / (1.0f + __expf(-(acc[1][mi][ni][r] + bgf)));
                out[idx] = gi * iQ[idx] + gf * b2f(ffn[idx]);
            }
        }
    }
}

// ---------------------------------------------------------------------------
extern "C" void kernel_launch(void* const* d_in, const int* in_sizes, int n_in,
                              void* d_out, int out_size, void* d_ws, size_t ws_size,
                              hipStream_t stream) {
    const int B = 4, S = 2048, D = 1024, D2 = 2048;
    const int M = B * S;  // 8192

    const float* iQ = (const float*)d_in[0];
    const float* iV = (const float*)d_in[1];
    const float* W1 = (const float*)d_in[2];
    const float* b1 = (const float*)d_in[3];
    const float* W2 = (const float*)d_in[4];
    const float* b2 = (const float*)d_in[5];
    const float* Wg = (const float*)d_in[6];
    const float* bg = (const float*)d_in[7];
    float* out = (float*)d_out;

    // workspace, no aliasing (61 MB):
    u16*   regA = (u16*)d_ws;                    // avg -> ffn   (16 MB)
    u16*   regB = regA + (size_t)M * D;          // h            (16 MB)
    u16*   iQb  = regB + (size_t)M * D;          // iQ bf16      (16 MB)
    u16*   W1t  = iQb  + (size_t)M * D;          //              ( 2 MB)
    u16*   W2t  = W1t  + (size_t)D * D;          //              ( 2 MB)
    u16*   Wgt  = W2t  + (size_t)D * D;          //              ( 8 MB)
    float* csum = (float*)(Wgt + (size_t)D2 * D2); // B*64*D f32 ( 1 MB)

    u16* avg = regA;
    u16* ffn = regA;
    u16* h   = regB;

    // 1. all independent prologue work in one big dispatch (14592 blocks)
    prologue_kernel<<<14592, 256, 0, stream>>>(W1, W1t, W2, W2t, Wg, Wgt,
                                               iQ, iQb, iV, csum);
    // 2. causal cumulative mean
    scan_kernel<<<B * 64, 256, 0, stream>>>(iV, csum, avg);
    // 3. h = relu(avg @ W1 + b1)
    gemm_kernel<0><<<dim3(M / 128, D / 128), 256, 0, stream>>>(avg, W1t, b1, h, M, D, D);
    // 4. ffn = h @ W2 + b2   (overlays avg)
    gemm_kernel<1><<<dim3(M / 128, D / 128), 256, 0, stream>>>(h, W2t, b2, ffn, M, D, D);
    // 5. fused gate GEMM + epilogue (BK=32, 2-row swizzle)
    gemm_gate_kernel<<<dim3(M / 128, D / 128), 256, 0, stream>>>(
        iQb, ffn, Wgt, bg, iQ, out, M, D2);
}